// Round 3
// baseline (614.715 us; speedup 1.0000x reference)
//
#include <hip/hip_runtime.h>
#include <cstddef>

#define Nn 50000
#define Ee 500000
#define INC 128
#define HC 256      // HEADS*OUT_C
#define OUTC 64
#define EDIM 32
#define NEG 0.2f
#define BK 32

// ---- ordered-uint encoding for float atomic max ----
__device__ __forceinline__ unsigned fenc(float f) {
    unsigned u = __float_as_uint(f);
    return (u & 0x80000000u) ? ~u : (u | 0x80000000u);
}
__device__ __forceinline__ float fdec(unsigned k) {
    unsigned u = (k & 0x80000000u) ? (k & 0x7FFFFFFFu) : ~k;
    return __uint_as_float(u);
}

// ---- K0: init out=bias, amax=0 (== -inf key), denom=0 ----
__global__ __launch_bounds__(256) void init_kernel(
    float* __restrict__ out, const float* __restrict__ bias,
    unsigned* __restrict__ amax, float* __restrict__ denom)
{
    int idx = blockIdx.x * 256 + threadIdx.x;
    if (idx < Nn * OUTC) out[idx] = bias[idx & (OUTC - 1)];
    if (idx < Nn * 4) { amax[idx] = 0u; denom[idx] = 0.f; }
}

// ---- K1: Y = X @ W + b, blockIdx.y selects (W_l,b_l)->Yl vs (W_r,b_r)->Yr ----
__global__ __launch_bounds__(256) void gemm_kernel(
    const float* __restrict__ X,
    const float* __restrict__ Wl, const float* __restrict__ bl,
    const float* __restrict__ Wr, const float* __restrict__ br,
    float* __restrict__ Yl, float* __restrict__ Yr)
{
    const float* W; const float* b; float* Y;
    if (blockIdx.y == 0) { W = Wl; b = bl; Y = Yl; } else { W = Wr; b = br; Y = Yr; }

    __shared__ float sA[64][36];
    __shared__ float sB[BK][256];

    const int row0 = blockIdx.x * 64;
    const int tid  = threadIdx.x;
    const int ty   = tid >> 4;
    const int tx   = tid & 15;

    float4 acc[4][4];
    #pragma unroll
    for (int i = 0; i < 4; ++i)
        #pragma unroll
        for (int j = 0; j < 4; ++j)
            acc[i][j] = make_float4(0.f, 0.f, 0.f, 0.f);

    #pragma unroll 1
    for (int k0 = 0; k0 < INC; k0 += BK) {
        if (k0) __syncthreads();
        #pragma unroll
        for (int it = 0; it < 2; ++it) {
            int idx = tid + it * 256;
            int r = idx >> 3, c = (idx & 7) << 2;
            float4 v = make_float4(0.f, 0.f, 0.f, 0.f);
            if (row0 + r < Nn) v = *(const float4*)(X + (size_t)(row0 + r) * INC + k0 + c);
            *(float4*)(&sA[r][c]) = v;
        }
        #pragma unroll
        for (int it = 0; it < 8; ++it) {
            int idx = tid + it * 256;
            int k = idx >> 6, c = (idx & 63) << 2;
            *(float4*)(&sB[k][c]) = *(const float4*)(W + (size_t)(k0 + k) * HC + c);
        }
        __syncthreads();

        #pragma unroll 1
        for (int kk = 0; kk < BK; kk += 4) {
            float4 a[4];
            #pragma unroll
            for (int i = 0; i < 4; ++i) a[i] = *(const float4*)(&sA[ty * 4 + i][kk]);
            #pragma unroll
            for (int t = 0; t < 4; ++t) {
                float4 bv[4];
                #pragma unroll
                for (int j = 0; j < 4; ++j)
                    bv[j] = *(const float4*)(&sB[kk + t][tx * 4 + j * 64]);
                #pragma unroll
                for (int i = 0; i < 4; ++i) {
                    float av = (t == 0) ? a[i].x : (t == 1) ? a[i].y : (t == 2) ? a[i].z : a[i].w;
                    #pragma unroll
                    for (int j = 0; j < 4; ++j) {
                        acc[i][j].x += av * bv[j].x;
                        acc[i][j].y += av * bv[j].y;
                        acc[i][j].z += av * bv[j].z;
                        acc[i][j].w += av * bv[j].w;
                    }
                }
            }
        }
    }

    float4 bs[4];
    #pragma unroll
    for (int j = 0; j < 4; ++j) bs[j] = *(const float4*)(b + tx * 4 + j * 64);
    #pragma unroll
    for (int i = 0; i < 4; ++i) {
        int grow = row0 + ty * 4 + i;
        if (grow < Nn) {
            #pragma unroll
            for (int j = 0; j < 4; ++j) {
                float4 o = make_float4(acc[i][j].x + bs[j].x, acc[i][j].y + bs[j].y,
                                       acc[i][j].z + bs[j].z, acc[i][j].w + bs[j].w);
                *(float4*)(Y + (size_t)grow * HC + tx * 4 + j * 64) = o;
            }
        }
    }
}

// ---- K2: per-edge logits, ONE EDGE PER THREAD ----
// ea[32] in VGPRs; We/att read at wave-uniform addresses (scalarized by the
// compiler -> s_load / broadcast, no LDS). Channels chunked by 32 (one head
// per chunk). All register arrays statically indexed (full unroll).
__global__ __launch_bounds__(256) void edge_alpha_kernel(
    const float* __restrict__ xl, const float* __restrict__ xr,
    const int* __restrict__ ei, const float* __restrict__ ea,
    const float* __restrict__ We, const float* __restrict__ att,
    float* __restrict__ alpha, unsigned* __restrict__ amax)
{
    int e = blockIdx.x * 256 + threadIdx.x;
    if (e >= Ee) return;
    int s = ei[e], d = ei[Ee + e];

    float ear[EDIM];
    #pragma unroll
    for (int i = 0; i < EDIM / 4; ++i) {
        float4 v = *(const float4*)(ea + (size_t)e * EDIM + i * 4);
        ear[i * 4 + 0] = v.x; ear[i * 4 + 1] = v.y;
        ear[i * 4 + 2] = v.z; ear[i * 4 + 3] = v.w;
    }

    const float* xls = xl + (size_t)s * HC;
    const float* xrd = xr + (size_t)d * HC;
    float p[4] = {0.f, 0.f, 0.f, 0.f};

    #pragma unroll 1
    for (int c0 = 0; c0 < HC; c0 += 32) {
        const int h = c0 >> 6;
        float m[32];
        #pragma unroll
        for (int j = 0; j < 8; ++j) {
            float4 a = *(const float4*)(xls + c0 + j * 4);
            float4 b = *(const float4*)(xrd + c0 + j * 4);
            m[j * 4 + 0] = a.x + b.x; m[j * 4 + 1] = a.y + b.y;
            m[j * 4 + 2] = a.z + b.z; m[j * 4 + 3] = a.w + b.w;
        }
        #pragma unroll
        for (int dd = 0; dd < EDIM; ++dd) {
            const float* wrow = We + (size_t)dd * HC + c0;   // wave-uniform
            #pragma unroll
            for (int j = 0; j < 32; ++j)
                m[j] += ear[dd] * wrow[j];
        }
        const float* ar = att + h * OUTC + (c0 & 63);        // wave-uniform
        float acc = 0.f;
        #pragma unroll
        for (int j = 0; j < 32; ++j) {
            float mm = m[j] > 0.f ? m[j] : NEG * m[j];
            acc += ar[j] * mm;
        }
        p[h] += acc;
    }

    *(float4*)(alpha + (size_t)e * 4) = make_float4(p[0], p[1], p[2], p[3]);
    #pragma unroll
    for (int h = 0; h < 4; ++h)
        atomicMax(amax + (size_t)d * 4 + h, fenc(p[h]));
}

// ---- K3: alpha <- exp(alpha - amax[dst]); denom[dst] += alpha ----
__global__ __launch_bounds__(256) void edge_exp_kernel(
    const int* __restrict__ ei, float* __restrict__ alpha,
    const unsigned* __restrict__ amax, float* __restrict__ denom)
{
    int idx = blockIdx.x * 256 + threadIdx.x;
    if (idx >= Ee * 4) return;
    int e = idx >> 2, h = idx & 3;
    int d = ei[Ee + e];
    float mx = fdec(amax[(size_t)d * 4 + h]);
    float v = __expf(alpha[idx] - mx);
    alpha[idx] = v;
    atomicAdd(denom + (size_t)d * 4 + h, v);
}

// ---- K4: out[dst,c] += 0.25 * sum_h (alpha/denom) * xl[src,h,c] ----
__global__ __launch_bounds__(256) void edge_aggr_kernel(
    const float* __restrict__ xl, const int* __restrict__ ei,
    const float* __restrict__ alpha, const float* __restrict__ denom,
    float* __restrict__ out)
{
    int lane = threadIdx.x & 63;
    int e = blockIdx.x * 4 + (threadIdx.x >> 6);
    if (e >= Ee) return;
    int s = ei[e], d = ei[Ee + e];
    float acc = 0.f;
    #pragma unroll
    for (int h = 0; h < 4; ++h) {
        float w = 0.25f * alpha[(size_t)e * 4 + h] / denom[(size_t)d * 4 + h];
        acc += w * xl[(size_t)s * HC + h * OUTC + lane];
    }
    atomicAdd(out + (size_t)d * OUTC + lane, acc);
}

extern "C" void kernel_launch(void* const* d_in, const int* in_sizes, int n_in,
                              void* d_out, int out_size, void* d_ws, size_t ws_size,
                              hipStream_t stream)
{
    const float* x    = (const float*)d_in[0];
    const int*   ei   = (const int*)d_in[1];
    const float* ea   = (const float*)d_in[2];
    const float* Wl   = (const float*)d_in[3];
    const float* bl   = (const float*)d_in[4];
    const float* Wr   = (const float*)d_in[5];
    const float* br   = (const float*)d_in[6];
    const float* We   = (const float*)d_in[7];
    const float* att  = (const float*)d_in[8];
    const float* bias = (const float*)d_in[9];
    float* out = (float*)d_out;

    float*    xl    = (float*)d_ws;                        // N*256
    float*    xr    = xl + (size_t)Nn * HC;                // N*256
    float*    alpha = xr + (size_t)Nn * HC;                // E*4
    unsigned* amax  = (unsigned*)(alpha + (size_t)Ee * 4); // N*4
    float*    denom = (float*)(amax + (size_t)Nn * 4);     // N*4

    init_kernel<<<(Nn * OUTC + 255) / 256, 256, 0, stream>>>(out, bias, amax, denom);
    gemm_kernel<<<dim3((Nn + 63) / 64, 2), 256, 0, stream>>>(x, Wl, bl, Wr, br, xl, xr);
    edge_alpha_kernel<<<(Ee + 255) / 256, 256, 0, stream>>>(xl, xr, ei, ea, We, att, alpha, amax);
    edge_exp_kernel<<<(Ee * 4 + 255) / 256, 256, 0, stream>>>(ei, alpha, amax, denom);
    edge_aggr_kernel<<<(Ee + 3) / 4, 256, 0, stream>>>(xl, ei, alpha, denom, out);
}

// Round 4
// 489.780 us; speedup vs baseline: 1.2551x; 1.2551x over previous
//
#include <hip/hip_runtime.h>
#include <cstddef>

#define Nn 50000
#define Ee 500000
#define INC 128
#define HC 256      // HEADS*OUT_C
#define OUTC 64
#define EDIM 32
#define NEG 0.2f
#define BK 32
#define TILE_E 128

// ---- ordered-uint encoding for float atomic max ----
__device__ __forceinline__ unsigned fenc(float f) {
    unsigned u = __float_as_uint(f);
    return (u & 0x80000000u) ? ~u : (u | 0x80000000u);
}
__device__ __forceinline__ float fdec(unsigned k) {
    unsigned u = (k & 0x80000000u) ? (k & 0x7FFFFFFFu) : ~k;
    return __uint_as_float(u);
}

// ---- K0: init out=bias, amax=0 (== -inf key), denom=0 ----
__global__ __launch_bounds__(256) void init_kernel(
    float* __restrict__ out, const float* __restrict__ bias,
    unsigned* __restrict__ amax, float* __restrict__ denom)
{
    int idx = blockIdx.x * 256 + threadIdx.x;
    if (idx < Nn * OUTC) out[idx] = bias[idx & (OUTC - 1)];
    if (idx < Nn * 4) { amax[idx] = 0u; denom[idx] = 0.f; }
}

// ---- K1: Y = X @ W + b, blockIdx.y selects (W_l,b_l)->Yl vs (W_r,b_r)->Yr ----
__global__ __launch_bounds__(256) void gemm_kernel(
    const float* __restrict__ X,
    const float* __restrict__ Wl, const float* __restrict__ bl,
    const float* __restrict__ Wr, const float* __restrict__ br,
    float* __restrict__ Yl, float* __restrict__ Yr)
{
    const float* W; const float* b; float* Y;
    if (blockIdx.y == 0) { W = Wl; b = bl; Y = Yl; } else { W = Wr; b = br; Y = Yr; }

    __shared__ float sA[64][36];
    __shared__ float sB[BK][256];

    const int row0 = blockIdx.x * 64;
    const int tid  = threadIdx.x;
    const int ty   = tid >> 4;
    const int tx   = tid & 15;

    float4 acc[4][4];
    #pragma unroll
    for (int i = 0; i < 4; ++i)
        #pragma unroll
        for (int j = 0; j < 4; ++j)
            acc[i][j] = make_float4(0.f, 0.f, 0.f, 0.f);

    #pragma unroll 1
    for (int k0 = 0; k0 < INC; k0 += BK) {
        if (k0) __syncthreads();
        #pragma unroll
        for (int it = 0; it < 2; ++it) {
            int idx = tid + it * 256;
            int r = idx >> 3, c = (idx & 7) << 2;
            float4 v = make_float4(0.f, 0.f, 0.f, 0.f);
            if (row0 + r < Nn) v = *(const float4*)(X + (size_t)(row0 + r) * INC + k0 + c);
            *(float4*)(&sA[r][c]) = v;
        }
        #pragma unroll
        for (int it = 0; it < 8; ++it) {
            int idx = tid + it * 256;
            int k = idx >> 6, c = (idx & 63) << 2;
            *(float4*)(&sB[k][c]) = *(const float4*)(W + (size_t)(k0 + k) * HC + c);
        }
        __syncthreads();

        #pragma unroll 1
        for (int kk = 0; kk < BK; kk += 4) {
            float4 a[4];
            #pragma unroll
            for (int i = 0; i < 4; ++i) a[i] = *(const float4*)(&sA[ty * 4 + i][kk]);
            #pragma unroll
            for (int t = 0; t < 4; ++t) {
                float4 bv[4];
                #pragma unroll
                for (int j = 0; j < 4; ++j)
                    bv[j] = *(const float4*)(&sB[kk + t][tx * 4 + j * 64]);
                #pragma unroll
                for (int i = 0; i < 4; ++i) {
                    float av = (t == 0) ? a[i].x : (t == 1) ? a[i].y : (t == 2) ? a[i].z : a[i].w;
                    #pragma unroll
                    for (int j = 0; j < 4; ++j) {
                        acc[i][j].x += av * bv[j].x;
                        acc[i][j].y += av * bv[j].y;
                        acc[i][j].z += av * bv[j].z;
                        acc[i][j].w += av * bv[j].w;
                    }
                }
            }
        }
    }

    float4 bs[4];
    #pragma unroll
    for (int j = 0; j < 4; ++j) bs[j] = *(const float4*)(b + tx * 4 + j * 64);
    #pragma unroll
    for (int i = 0; i < 4; ++i) {
        int grow = row0 + ty * 4 + i;
        if (grow < Nn) {
            #pragma unroll
            for (int j = 0; j < 4; ++j) {
                float4 o = make_float4(acc[i][j].x + bs[j].x, acc[i][j].y + bs[j].y,
                                       acc[i][j].z + bs[j].z, acc[i][j].w + bs[j].w);
                *(float4*)(Y + (size_t)grow * HC + tx * 4 + j * 64) = o;
            }
        }
    }
}

// ---- K2: per-edge logits as a register-blocked tiled GEMM ----
// Block = 128 edges. sEaT (transposed ea tile) + full We in LDS.
// Thread (te=tid>>4, tc=tid&15): 8 edges x 4 cols. Per head-block cb (64 cols):
//   gathers issued early (coalesced across tc), e-GEMM k-loop (VALU-bound,
//   LDS reads broadcast/2-way = free), epilogue leaky+att-dot, shfl reduce
//   over the 16 tc lanes, tc==0 stores alpha + atomicMax(amax).
__global__ __launch_bounds__(256, 3) void edge_alpha_kernel(
    const float* __restrict__ xl, const float* __restrict__ xr,
    const int* __restrict__ ei, const float* __restrict__ ea,
    const float* __restrict__ We, const float* __restrict__ att,
    float* __restrict__ alpha, unsigned* __restrict__ amax)
{
    __shared__ float sEaT[EDIM][132];   // 16.9 KB, [k][edge_local]
    __shared__ float sWe[EDIM][260];    // 33.3 KB
    __shared__ int   sS[TILE_E], sD[TILE_E];

    const int tid = threadIdx.x;
    const int e0  = blockIdx.x * TILE_E;

    // stage We: 32x256 floats = 2048 float4, 8 per thread (coalesced)
    #pragma unroll
    for (int it = 0; it < 8; ++it) {
        int idx = tid + it * 256;
        int k = idx >> 6, c = (idx & 63) << 2;
        float4 v = *(const float4*)(We + (size_t)k * HC + c);
        *(float4*)(&sWe[k][c]) = v;
    }
    // stage edge indices
    if (tid < TILE_E) {
        int e = e0 + tid;
        sS[tid] = (e < Ee) ? ei[e] : 0;
        sD[tid] = (e < Ee) ? ei[Ee + e] : 0;
    }
    // stage ea tile transposed: thread t covers edge r=t>>1, cols (t&1)*16 + j*4
    {
        int r = tid >> 1, cbase = (tid & 1) * 16;
        int e = e0 + r;
        #pragma unroll
        for (int j = 0; j < 4; ++j) {
            float4 v = make_float4(0.f, 0.f, 0.f, 0.f);
            if (e < Ee) v = *(const float4*)(ea + (size_t)e * EDIM + cbase + j * 4);
            sEaT[cbase + j * 4 + 0][r] = v.x;
            sEaT[cbase + j * 4 + 1][r] = v.y;
            sEaT[cbase + j * 4 + 2][r] = v.z;
            sEaT[cbase + j * 4 + 3][r] = v.w;
        }
    }
    __syncthreads();

    const int te = tid >> 4;
    const int tc = tid & 15;
    int s[8], d[8];
    #pragma unroll
    for (int i = 0; i < 8; ++i) { s[i] = sS[te * 8 + i]; d[i] = sD[te * 8 + i]; }

    const float4* xl4 = (const float4*)xl;
    const float4* xr4 = (const float4*)xr;

    #pragma unroll 1
    for (int cb = 0; cb < 4; ++cb) {
        // issue gathers early: coalesced (16 tc lanes -> 256B per (edge,i))
        float4 gl[8], gr[8];
        #pragma unroll
        for (int i = 0; i < 8; ++i) {
            gl[i] = xl4[(size_t)s[i] * 64 + cb * 16 + tc];
            gr[i] = xr4[(size_t)d[i] * 64 + cb * 16 + tc];
        }

        float4 acc[8];
        #pragma unroll
        for (int i = 0; i < 8; ++i) acc[i] = make_float4(0.f, 0.f, 0.f, 0.f);

        #pragma unroll 2
        for (int k = 0; k < EDIM; ++k) {
            float4 w  = *(const float4*)(&sWe[k][cb * 64 + tc * 4]);
            float4 aA = *(const float4*)(&sEaT[k][te * 8]);
            float4 aB = *(const float4*)(&sEaT[k][te * 8 + 4]);
            acc[0].x += aA.x * w.x; acc[0].y += aA.x * w.y; acc[0].z += aA.x * w.z; acc[0].w += aA.x * w.w;
            acc[1].x += aA.y * w.x; acc[1].y += aA.y * w.y; acc[1].z += aA.y * w.z; acc[1].w += aA.y * w.w;
            acc[2].x += aA.z * w.x; acc[2].y += aA.z * w.y; acc[2].z += aA.z * w.z; acc[2].w += aA.z * w.w;
            acc[3].x += aA.w * w.x; acc[3].y += aA.w * w.y; acc[3].z += aA.w * w.z; acc[3].w += aA.w * w.w;
            acc[4].x += aB.x * w.x; acc[4].y += aB.x * w.y; acc[4].z += aB.x * w.z; acc[4].w += aB.x * w.w;
            acc[5].x += aB.y * w.x; acc[5].y += aB.y * w.y; acc[5].z += aB.y * w.z; acc[5].w += aB.y * w.w;
            acc[6].x += aB.z * w.x; acc[6].y += aB.z * w.y; acc[6].z += aB.z * w.z; acc[6].w += aB.z * w.w;
            acc[7].x += aB.w * w.x; acc[7].y += aB.w * w.y; acc[7].z += aB.w * w.z; acc[7].w += aB.w * w.w;
        }

        float4 at4 = *(const float4*)(att + cb * 64 + tc * 4);
        #pragma unroll
        for (int i = 0; i < 8; ++i) {
            float4 m;
            m.x = acc[i].x + gl[i].x + gr[i].x;
            m.y = acc[i].y + gl[i].y + gr[i].y;
            m.z = acc[i].z + gl[i].z + gr[i].z;
            m.w = acc[i].w + gl[i].w + gr[i].w;
            m.x = fmaxf(m.x, NEG * m.x);
            m.y = fmaxf(m.y, NEG * m.y);
            m.z = fmaxf(m.z, NEG * m.z);
            m.w = fmaxf(m.w, NEG * m.w);
            float v = at4.x * m.x + at4.y * m.y + at4.z * m.z + at4.w * m.w;
            v += __shfl_xor(v, 1, 64);
            v += __shfl_xor(v, 2, 64);
            v += __shfl_xor(v, 4, 64);
            v += __shfl_xor(v, 8, 64);
            if (tc == 0) {
                int e = e0 + te * 8 + i;
                if (e < Ee) {
                    alpha[(size_t)e * 4 + cb] = v;
                    atomicMax(amax + (size_t)d[i] * 4 + cb, fenc(v));
                }
            }
        }
    }
}

// ---- K3: alpha <- exp(alpha - amax[dst]); denom[dst] += alpha ----
__global__ __launch_bounds__(256) void edge_exp_kernel(
    const int* __restrict__ ei, float* __restrict__ alpha,
    const unsigned* __restrict__ amax, float* __restrict__ denom)
{
    int idx = blockIdx.x * 256 + threadIdx.x;
    if (idx >= Ee * 4) return;
    int e = idx >> 2, h = idx & 3;
    int d = ei[Ee + e];
    float mx = fdec(amax[(size_t)d * 4 + h]);
    float v = __expf(alpha[idx] - mx);
    alpha[idx] = v;
    atomicAdd(denom + (size_t)d * 4 + h, v);
}

// ---- K4: out[dst,c] += 0.25 * sum_h (alpha/denom) * xl[src,h,c] ----
__global__ __launch_bounds__(256) void edge_aggr_kernel(
    const float* __restrict__ xl, const int* __restrict__ ei,
    const float* __restrict__ alpha, const float* __restrict__ denom,
    float* __restrict__ out)
{
    int lane = threadIdx.x & 63;
    int e = blockIdx.x * 4 + (threadIdx.x >> 6);
    if (e >= Ee) return;
    int s = ei[e], d = ei[Ee + e];
    float acc = 0.f;
    #pragma unroll
    for (int h = 0; h < 4; ++h) {
        float w = 0.25f * alpha[(size_t)e * 4 + h] / denom[(size_t)d * 4 + h];
        acc += w * xl[(size_t)s * HC + h * OUTC + lane];
    }
    atomicAdd(out + (size_t)d * OUTC + lane, acc);
}

extern "C" void kernel_launch(void* const* d_in, const int* in_sizes, int n_in,
                              void* d_out, int out_size, void* d_ws, size_t ws_size,
                              hipStream_t stream)
{
    const float* x    = (const float*)d_in[0];
    const int*   ei   = (const int*)d_in[1];
    const float* ea   = (const float*)d_in[2];
    const float* Wl   = (const float*)d_in[3];
    const float* bl   = (const float*)d_in[4];
    const float* Wr   = (const float*)d_in[5];
    const float* br   = (const float*)d_in[6];
    const float* We   = (const float*)d_in[7];
    const float* att  = (const float*)d_in[8];
    const float* bias = (const float*)d_in[9];
    float* out = (float*)d_out;

    float*    xl    = (float*)d_ws;                        // N*256
    float*    xr    = xl + (size_t)Nn * HC;                // N*256
    float*    alpha = xr + (size_t)Nn * HC;                // E*4
    unsigned* amax  = (unsigned*)(alpha + (size_t)Ee * 4); // N*4
    float*    denom = (float*)(amax + (size_t)Nn * 4);     // N*4

    init_kernel<<<(Nn * OUTC + 255) / 256, 256, 0, stream>>>(out, bias, amax, denom);
    gemm_kernel<<<dim3((Nn + 63) / 64, 2), 256, 0, stream>>>(x, Wl, bl, Wr, br, xl, xr);
    edge_alpha_kernel<<<(Ee + TILE_E - 1) / TILE_E, 256, 0, stream>>>(xl, xr, ei, ea, We, att, alpha, amax);
    edge_exp_kernel<<<(Ee * 4 + 255) / 256, 256, 0, stream>>>(ei, alpha, amax, denom);
    edge_aggr_kernel<<<(Ee + 3) / 4, 256, 0, stream>>>(xl, ei, alpha, denom, out);
}

// Round 5
// 353.860 us; speedup vs baseline: 1.7372x; 1.3841x over previous
//
#include <hip/hip_runtime.h>
#include <cstddef>

#define Nn 50000
#define Ee 500000
#define INC 128
#define HC 256      // HEADS*OUT_C
#define OUTC 64
#define EDIM 32
#define NEG 0.2f
#define BK 32

typedef __attribute__((ext_vector_type(8))) short short8;   // 8 bf16 = 4 VGPR
typedef __attribute__((ext_vector_type(4))) float f32x4;

// ---- bf16 helpers (RNE) ----
__device__ __forceinline__ unsigned short f2bf(float f) {
    unsigned u = __float_as_uint(f);
    return (unsigned short)((u + 0x7FFFu + ((u >> 16) & 1u)) >> 16);
}
__device__ __forceinline__ float bf2f(unsigned short v) {
    return __uint_as_float(((unsigned)v) << 16);
}

// ---- ordered-uint encoding for float atomic max ----
__device__ __forceinline__ unsigned fenc(float f) {
    unsigned u = __float_as_uint(f);
    return (u & 0x80000000u) ? ~u : (u | 0x80000000u);
}
__device__ __forceinline__ float fdec(unsigned k) {
    unsigned u = (k & 0x80000000u) ? (k & 0x7FFFFFFFu) : ~k;
    return __uint_as_float(u);
}

// ---- K0: init out=bias, amax=0 (== -inf key), denom=0 ----
__global__ __launch_bounds__(256) void init_kernel(
    float* __restrict__ out, const float* __restrict__ bias,
    unsigned* __restrict__ amax, float* __restrict__ denom)
{
    int idx = blockIdx.x * 256 + threadIdx.x;
    if (idx < Nn * OUTC) out[idx] = bias[idx & (OUTC - 1)];
    if (idx < Nn * 4) { amax[idx] = 0u; denom[idx] = 0.f; }
}

// ---- K_we: pre-pack We into MFMA B-frag order, bf16 ----
// slot sid = (cb*4 + nt)*64 + lane; data[j] = We[(lane>>4)*8 + j][cb*64 + nt*16 + (lane&15)]
__global__ __launch_bounds__(256) void we_frag_kernel(
    const float* __restrict__ We, unsigned short* __restrict__ wef)
{
    int sid = blockIdx.x * 256 + threadIdx.x;
    if (sid >= 1024) return;
    int lane = sid & 63, nt = (sid >> 6) & 3, cb = sid >> 8;
    int col = cb * 64 + nt * 16 + (lane & 15);
    int k0 = (lane >> 4) * 8;
    unsigned short tmp[8];
    #pragma unroll
    for (int j = 0; j < 8; ++j) tmp[j] = f2bf(We[(size_t)(k0 + j) * HC + col]);
    *(uint4*)(wef + (size_t)sid * 8) = *(uint4*)tmp;
}

// ---- K1: Y = X @ W + b; y==0 -> xl (f32) + xlb (bf16); y==1 -> xrb (bf16 only) ----
__global__ __launch_bounds__(256) void gemm_kernel(
    const float* __restrict__ X,
    const float* __restrict__ Wl, const float* __restrict__ bl,
    const float* __restrict__ Wr, const float* __restrict__ br,
    float* __restrict__ Yl, unsigned short* __restrict__ Ylb,
    unsigned short* __restrict__ Yrb)
{
    const float* W; const float* b; unsigned short* Yb;
    if (blockIdx.y == 0) { W = Wl; b = bl; Yb = Ylb; } else { W = Wr; b = br; Yb = Yrb; }

    __shared__ float sA[64][36];
    __shared__ float sB[BK][256];

    const int row0 = blockIdx.x * 64;
    const int tid  = threadIdx.x;
    const int ty   = tid >> 4;
    const int tx   = tid & 15;

    float4 acc[4][4];
    #pragma unroll
    for (int i = 0; i < 4; ++i)
        #pragma unroll
        for (int j = 0; j < 4; ++j)
            acc[i][j] = make_float4(0.f, 0.f, 0.f, 0.f);

    #pragma unroll 1
    for (int k0 = 0; k0 < INC; k0 += BK) {
        if (k0) __syncthreads();
        #pragma unroll
        for (int it = 0; it < 2; ++it) {
            int idx = tid + it * 256;
            int r = idx >> 3, c = (idx & 7) << 2;
            float4 v = make_float4(0.f, 0.f, 0.f, 0.f);
            if (row0 + r < Nn) v = *(const float4*)(X + (size_t)(row0 + r) * INC + k0 + c);
            *(float4*)(&sA[r][c]) = v;
        }
        #pragma unroll
        for (int it = 0; it < 8; ++it) {
            int idx = tid + it * 256;
            int k = idx >> 6, c = (idx & 63) << 2;
            *(float4*)(&sB[k][c]) = *(const float4*)(W + (size_t)(k0 + k) * HC + c);
        }
        __syncthreads();

        #pragma unroll 1
        for (int kk = 0; kk < BK; kk += 4) {
            float4 a[4];
            #pragma unroll
            for (int i = 0; i < 4; ++i) a[i] = *(const float4*)(&sA[ty * 4 + i][kk]);
            #pragma unroll
            for (int t = 0; t < 4; ++t) {
                float4 bv[4];
                #pragma unroll
                for (int j = 0; j < 4; ++j)
                    bv[j] = *(const float4*)(&sB[kk + t][tx * 4 + j * 64]);
                #pragma unroll
                for (int i = 0; i < 4; ++i) {
                    float av = (t == 0) ? a[i].x : (t == 1) ? a[i].y : (t == 2) ? a[i].z : a[i].w;
                    #pragma unroll
                    for (int j = 0; j < 4; ++j) {
                        acc[i][j].x += av * bv[j].x;
                        acc[i][j].y += av * bv[j].y;
                        acc[i][j].z += av * bv[j].z;
                        acc[i][j].w += av * bv[j].w;
                    }
                }
            }
        }
    }

    float4 bs[4];
    #pragma unroll
    for (int j = 0; j < 4; ++j) bs[j] = *(const float4*)(b + tx * 4 + j * 64);
    #pragma unroll
    for (int i = 0; i < 4; ++i) {
        int grow = row0 + ty * 4 + i;
        if (grow < Nn) {
            #pragma unroll
            for (int j = 0; j < 4; ++j) {
                float4 o = make_float4(acc[i][j].x + bs[j].x, acc[i][j].y + bs[j].y,
                                       acc[i][j].z + bs[j].z, acc[i][j].w + bs[j].w);
                if (blockIdx.y == 0)
                    *(float4*)(Yl + (size_t)grow * HC + tx * 4 + j * 64) = o;
                ushort4 ob;
                ob.x = f2bf(o.x); ob.y = f2bf(o.y); ob.z = f2bf(o.z); ob.w = f2bf(o.w);
                *(ushort4*)(Yb + (size_t)grow * HC + tx * 4 + j * 64) = ob;
            }
        }
    }
}

// ---- K2: per-edge logits via MFMA bf16, no LDS ----
// Block = 128 edges = 4 waves x 32 edges (2 M-tiles). Per cb (64 cols = 4 N-tiles):
// e-term = mfma_16x16x32_bf16(A=ea_tile, B=We_frag), C layout col=lane&15,
// row=(lane>>4)*4+reg. Epilogue gathers xlb/xrb (bf16, 2B), leaky, att-dot,
// 16-lane shfl reduce, store alpha + atomicMax(amax).
__global__ __launch_bounds__(256, 3) void edge_alpha_kernel(
    const unsigned short* __restrict__ xlb, const unsigned short* __restrict__ xrb,
    const int* __restrict__ ei, const float* __restrict__ ea,
    const unsigned short* __restrict__ wef, const float* __restrict__ att,
    float* __restrict__ alpha, unsigned* __restrict__ amax)
{
    const int tid  = threadIdx.x;
    const int lane = tid & 63;
    const int l15  = lane & 15, l4 = lane >> 4;
    const int e0   = blockIdx.x * 128 + (tid >> 6) * 32;

    // A-frags: 2 tiles of 16 edges; lane holds ea[e0+mt*16+l15][l4*8 .. +7]
    short8 afrag[2];
    #pragma unroll
    for (int mt = 0; mt < 2; ++mt) {
        int e = e0 + mt * 16 + l15;
        if (e >= Ee) e = 0;
        const float* p = ea + (size_t)e * EDIM + l4 * 8;
        float4 v0 = *(const float4*)p;
        float4 v1 = *(const float4*)(p + 4);
        short8 a;
        a[0] = (short)f2bf(v0.x); a[1] = (short)f2bf(v0.y);
        a[2] = (short)f2bf(v0.z); a[3] = (short)f2bf(v0.w);
        a[4] = (short)f2bf(v1.x); a[5] = (short)f2bf(v1.y);
        a[6] = (short)f2bf(v1.z); a[7] = (short)f2bf(v1.w);
        afrag[mt] = a;
    }

    // per-slot edge ids and node row offsets (slot = mt*4 + r)
    unsigned soff[8], doff[8];
    #pragma unroll
    for (int mt = 0; mt < 2; ++mt)
        #pragma unroll
        for (int r = 0; r < 4; ++r) {
            int idx = mt * 4 + r;
            int e = e0 + mt * 16 + l4 * 4 + r;
            int ec = (e < Ee) ? e : 0;
            soff[idx] = (unsigned)ei[ec] * (unsigned)HC;
            doff[idx] = (unsigned)ei[Ee + ec] * (unsigned)HC;
        }

    // att values for this lane's columns, all 4 cb hoisted
    float attv[4][4];
    #pragma unroll
    for (int cb = 0; cb < 4; ++cb)
        #pragma unroll
        for (int nt = 0; nt < 4; ++nt)
            attv[cb][nt] = att[cb * 64 + nt * 16 + l15];

    #pragma unroll 1
    for (int cb = 0; cb < 4; ++cb) {
        short8 bfrag[4];
        #pragma unroll
        for (int nt = 0; nt < 4; ++nt)
            bfrag[nt] = *(const short8*)(wef + ((size_t)(cb * 4 + nt) * 64 + lane) * 8);

        f32x4 acc[2][4];
        const f32x4 z = {0.f, 0.f, 0.f, 0.f};
        #pragma unroll
        for (int mt = 0; mt < 2; ++mt)
            #pragma unroll
            for (int nt = 0; nt < 4; ++nt)
                acc[mt][nt] = __builtin_amdgcn_mfma_f32_16x16x32_bf16(
                    afrag[mt], bfrag[nt], z, 0, 0, 0);

        #pragma unroll
        for (int mt = 0; mt < 2; ++mt) {
            #pragma unroll
            for (int r = 0; r < 4; ++r) {
                const int idx = mt * 4 + r;
                float p = 0.f;
                #pragma unroll
                for (int nt = 0; nt < 4; ++nt) {
                    unsigned c = (unsigned)(cb * 64 + nt * 16 + l15);
                    float xv = bf2f(xlb[soff[idx] + c]);
                    float yv = bf2f(xrb[doff[idx] + c]);
                    float m = acc[mt][nt][r] + xv + yv;
                    m = fmaxf(m, NEG * m);
                    p = fmaf(attv[cb][nt], m, p);
                }
                p += __shfl_xor(p, 1, 64);
                p += __shfl_xor(p, 2, 64);
                p += __shfl_xor(p, 4, 64);
                p += __shfl_xor(p, 8, 64);
                int e = e0 + mt * 16 + l4 * 4 + r;
                if (l15 == 0 && e < Ee) {
                    alpha[(size_t)e * 4 + cb] = p;
                    atomicMax(amax + (size_t)(doff[idx] >> 8) * 4 + cb, fenc(p));
                }
            }
        }
    }
}

// ---- K3: alpha <- exp(alpha - amax[dst]); denom[dst] += alpha ----
__global__ __launch_bounds__(256) void edge_exp_kernel(
    const int* __restrict__ ei, float* __restrict__ alpha,
    const unsigned* __restrict__ amax, float* __restrict__ denom)
{
    int idx = blockIdx.x * 256 + threadIdx.x;
    if (idx >= Ee * 4) return;
    int e = idx >> 2, h = idx & 3;
    int d = ei[Ee + e];
    float mx = fdec(amax[(size_t)d * 4 + h]);
    float v = __expf(alpha[idx] - mx);
    alpha[idx] = v;
    atomicAdd(denom + (size_t)d * 4 + h, v);
}

// ---- K4: out[dst,c] += 0.25 * sum_h (alpha/denom) * xl[src,h,c] ----
__global__ __launch_bounds__(256) void edge_aggr_kernel(
    const float* __restrict__ xl, const int* __restrict__ ei,
    const float* __restrict__ alpha, const float* __restrict__ denom,
    float* __restrict__ out)
{
    int lane = threadIdx.x & 63;
    int e = blockIdx.x * 4 + (threadIdx.x >> 6);
    if (e >= Ee) return;
    int s = ei[e], d = ei[Ee + e];
    float acc = 0.f;
    #pragma unroll
    for (int h = 0; h < 4; ++h) {
        float w = 0.25f * alpha[(size_t)e * 4 + h] / denom[(size_t)d * 4 + h];
        acc += w * xl[(size_t)s * HC + h * OUTC + lane];
    }
    atomicAdd(out + (size_t)d * OUTC + lane, acc);
}

extern "C" void kernel_launch(void* const* d_in, const int* in_sizes, int n_in,
                              void* d_out, int out_size, void* d_ws, size_t ws_size,
                              hipStream_t stream)
{
    const float* x    = (const float*)d_in[0];
    const int*   ei   = (const int*)d_in[1];
    const float* ea   = (const float*)d_in[2];
    const float* Wl   = (const float*)d_in[3];
    const float* bl   = (const float*)d_in[4];
    const float* Wr   = (const float*)d_in[5];
    const float* br   = (const float*)d_in[6];
    const float* We   = (const float*)d_in[7];
    const float* att  = (const float*)d_in[8];
    const float* bias = (const float*)d_in[9];
    float* out = (float*)d_out;

    // workspace layout (~112 MB)
    float*          xl    = (float*)d_ws;                          // N*256 f32
    unsigned short* xlb   = (unsigned short*)(xl + (size_t)Nn * HC);   // N*256 bf16
    unsigned short* xrb   = xlb + (size_t)Nn * HC;                 // N*256 bf16
    float*          alpha = (float*)(xrb + (size_t)Nn * HC);       // E*4
    unsigned*       amax  = (unsigned*)(alpha + (size_t)Ee * 4);   // N*4
    float*          denom = (float*)(amax + (size_t)Nn * 4);       // N*4
    unsigned short* wef   = (unsigned short*)(denom + (size_t)Nn * 4); // 8192 bf16

    init_kernel<<<(Nn * OUTC + 255) / 256, 256, 0, stream>>>(out, bias, amax, denom);
    we_frag_kernel<<<4, 256, 0, stream>>>(We, wef);
    gemm_kernel<<<dim3((Nn + 63) / 64, 2), 256, 0, stream>>>(x, Wl, bl, Wr, br, xl, xlb, xrb);
    edge_alpha_kernel<<<(Ee + 127) / 128, 256, 0, stream>>>(xlb, xrb, ei, ea, wef, att, alpha, amax);
    edge_exp_kernel<<<(Ee * 4 + 255) / 256, 256, 0, stream>>>(ei, alpha, amax, denom);
    edge_aggr_kernel<<<(Ee + 3) / 4, 256, 0, stream>>>(xl, ei, alpha, denom, out);
}